// Round 12
// baseline (311.389 us; speedup 1.0000x reference)
//
#include <hip/hip_runtime.h>

typedef __attribute__((ext_vector_type(4))) float f32x4;
typedef __attribute__((ext_vector_type(8))) float f32x8;
typedef __attribute__((ext_vector_type(8))) short bf16x8;
typedef __attribute__((ext_vector_type(2))) uint u32x2;

#define SCALE_ 0.17677669529663687f

__device__ __forceinline__ float bf2f(ushort u){
  union { unsigned i; float f; } v; v.i = ((unsigned)u) << 16; return v.f;
}
__device__ __forceinline__ ushort f2bf(float f){
  union { float f; unsigned i; } v; v.f = f;
  unsigned r = v.i + 0x7fffu + ((v.i >> 16) & 1u);
  return (ushort)(r >> 16);
}
__device__ __forceinline__ void gl16(const void* g, const ushort* l) {
  __builtin_amdgcn_global_load_lds((const __attribute__((address_space(1))) uint*)g,
                                   (__attribute__((address_space(3))) uint*)l, 16, 0, 0);
}

// ---------------------------------------------------------------- prep (+ fused wprep tail blocks)
__global__ __launch_bounds__(256) void k_prep(const float* __restrict__ x,
    const float* __restrict__ gt, const float* __restrict__ qw,
    const float* __restrict__ kvw, const float* __restrict__ pw,
    const float* __restrict__ srw, ushort* __restrict__ xc,
    ushort* __restrict__ xkv, float* __restrict__ out2,
    ushort* __restrict__ wq, ushort* __restrict__ wkv,
    ushort* __restrict__ wpr, ushort* __restrict__ wcv)
{
  int blk = blockIdx.x;
  if (blk >= 66560) {                       // wprep role
    int i = (blk - 66560) * 256 + threadIdx.x;   // 0..524287
    if (i < 65536)            wq[i] = f2bf(qw[i]);
    else if (i < 196608)      wkv[i - 65536] = f2bf(kvw[i - 65536]);
    else if (i < 262144)      wpr[i - 196608] = f2bf(pw[i - 196608]);
    else {
      int j = i - 262144;
      int o = j >> 10, t = (j >> 8) & 3, cc = j & 255;
      wcv[j] = f2bf(srw[o * 1024 + cc * 4 + t]);
    }
    return;
  }
  int row = blk;                   // 0..66559
  int c = threadIdx.x;
  int wi = row / 65, n = row - wi * 65;
  if (n == 0) {
    float g = gt[(size_t)wi * 256 + c];
    ushort gb = f2bf(g);
    xc[(size_t)row * 256 + c] = gb;
    xkv[(size_t)row * 256 + c] = gb;
    out2[(size_t)wi * 256 + c] = g;
  } else {
    int s = n - 1, r = s >> 3, cc = s & 7;
    int b = wi >> 8, wh = (wi >> 4) & 15, ww = wi & 15;
    int hw = (wh * 8 + r) * 128 + ww * 8 + cc;
    xc[(size_t)row * 256 + c] = f2bf(x[((size_t)b * 16384 + hw) * 256 + c]);
  }
}

// ---------------------------------------------------------------- tiled GEMM (m97 structure + XCD swizzle)
template<int N>
__global__ __launch_bounds__(256) void k_gemm2(const ushort* __restrict__ A,
    const ushort* __restrict__ W, const float* __restrict__ bias,
    ushort* __restrict__ C)
{
  constexpr int K = 256;
  __shared__ __align__(16) ushort As[2][128 * 64];
  __shared__ __align__(16) ushort Bs[2][128 * 64];
  int lin = blockIdx.y * gridDim.x + blockIdx.x;
  int qq = (gridDim.x * gridDim.y) >> 3;
  int sw2 = (lin & 7) * qq + (lin >> 3);
  int m0 = (sw2 / gridDim.x) * 128, n0 = (sw2 % gridDim.x) * 128;
  int tid = threadIdx.x, lane = tid & 63;
  int wave = tid >> 6;
  int lm = lane & 15, kg = lane >> 4;
  int wr = wave >> 1, wc = wave & 1;

  const char* Ab = (const char*)A + (size_t)m0 * (K * 2);
  const char* Bb = (const char*)W + (size_t)n0 * (K * 2);

  auto stage = [&](int buf, int kt) {
#pragma unroll
    for (int j = 0; j < 4; ++j) {
      int c = j * 256 + tid;            // chunk 0..1023
      int row = c >> 3, slot = c & 7;   // 8 x 16B per 128B row
      int srcoff = row * (K * 2) + kt * 128 + ((slot * 16) ^ ((row & 7) << 4));
      gl16(Ab + srcoff, (const ushort*)((const char*)As[buf] + c * 16));
      gl16(Bb + srcoff, (const ushort*)((const char*)Bs[buf] + c * 16));
    }
  };

  f32x4 acc[4][4];
  f32x4 zero = {0.f, 0.f, 0.f, 0.f};
#pragma unroll
  for (int a = 0; a < 4; ++a)
#pragma unroll
    for (int b = 0; b < 4; ++b) acc[a][b] = zero;

  stage(0, 0);
  __syncthreads();
#pragma unroll
  for (int t = 0; t < 4; ++t) {
    int cur = t & 1;
    if (t < 3) stage(cur ^ 1, t + 1);
#pragma unroll
    for (int s = 0; s < 2; ++s) {
      int sw = (lm & 7) << 4;
      bf16x8 af[4], bw[4];
#pragma unroll
      for (int mi = 0; mi < 4; ++mi) {
        int row = wr * 64 + mi * 16 + lm;
        af[mi] = *(const bf16x8*)((const char*)As[cur] + row * 128 + ((s * 64 + kg * 16) ^ sw));
      }
#pragma unroll
      for (int ni = 0; ni < 4; ++ni) {
        int row = wc * 64 + ni * 16 + lm;
        bw[ni] = *(const bf16x8*)((const char*)Bs[cur] + row * 128 + ((s * 64 + kg * 16) ^ sw));
      }
#pragma unroll
      for (int mi = 0; mi < 4; ++mi)
#pragma unroll
        for (int ni = 0; ni < 4; ++ni)
          acc[mi][ni] = __builtin_amdgcn_mfma_f32_16x16x32_bf16(af[mi], bw[ni], acc[mi][ni], 0, 0, 0);
    }
    __syncthreads();
  }

  int rbase = m0 + wr * 64 + kg * 4;
#pragma unroll
  for (int ni = 0; ni < 4; ++ni) {
    int col = n0 + wc * 64 + ni * 16 + lm;
    float bv = bias[col];
#pragma unroll
    for (int mi = 0; mi < 4; ++mi) {
#pragma unroll
      for (int r = 0; r < 4; ++r)
        C[(size_t)(rbase + mi * 16 + r) * N + col] = f2bf(acc[mi][ni][r] + bv);
    }
  }
}

// ---------------------------------------------------------------- proj GEMM with fused scatter epilogue
__global__ __launch_bounds__(256) void k_gemm_out(const ushort* __restrict__ A,
    const ushort* __restrict__ W, const float* __restrict__ bias,
    float* __restrict__ out)
{
  constexpr int K = 256;
  __shared__ __align__(16) ushort As[2][128 * 64];
  __shared__ __align__(16) ushort Bs[2][128 * 64];
  int lin = blockIdx.y * gridDim.x + blockIdx.x;
  int qq = (gridDim.x * gridDim.y) >> 3;
  int sw2 = (lin & 7) * qq + (lin >> 3);
  int m0 = (sw2 / gridDim.x) * 128, n0 = (sw2 % gridDim.x) * 128;
  int tid = threadIdx.x, lane = tid & 63;
  int wave = tid >> 6;
  int lm = lane & 15, kg = lane >> 4;
  int wr = wave >> 1, wc = wave & 1;

  const char* Ab = (const char*)A + (size_t)m0 * (K * 2);
  const char* Bb = (const char*)W + (size_t)n0 * (K * 2);

  auto stage = [&](int buf, int kt) {
#pragma unroll
    for (int j = 0; j < 4; ++j) {
      int c = j * 256 + tid;
      int row = c >> 3, slot = c & 7;
      int srcoff = row * (K * 2) + kt * 128 + ((slot * 16) ^ ((row & 7) << 4));
      gl16(Ab + srcoff, (const ushort*)((const char*)As[buf] + c * 16));
      gl16(Bb + srcoff, (const ushort*)((const char*)Bs[buf] + c * 16));
    }
  };

  f32x4 acc[4][4];
  f32x4 zero = {0.f, 0.f, 0.f, 0.f};
#pragma unroll
  for (int a = 0; a < 4; ++a)
#pragma unroll
    for (int b = 0; b < 4; ++b) acc[a][b] = zero;

  stage(0, 0);
  __syncthreads();
#pragma unroll
  for (int t = 0; t < 4; ++t) {
    int cur = t & 1;
    if (t < 3) stage(cur ^ 1, t + 1);
#pragma unroll
    for (int s = 0; s < 2; ++s) {
      int sw = (lm & 7) << 4;
      bf16x8 af[4], bw[4];
#pragma unroll
      for (int mi = 0; mi < 4; ++mi) {
        int row = wr * 64 + mi * 16 + lm;
        af[mi] = *(const bf16x8*)((const char*)As[cur] + row * 128 + ((s * 64 + kg * 16) ^ sw));
      }
#pragma unroll
      for (int ni = 0; ni < 4; ++ni) {
        int row = wc * 64 + ni * 16 + lm;
        bw[ni] = *(const bf16x8*)((const char*)Bs[cur] + row * 128 + ((s * 64 + kg * 16) ^ sw));
      }
#pragma unroll
      for (int mi = 0; mi < 4; ++mi)
#pragma unroll
        for (int ni = 0; ni < 4; ++ni)
          acc[mi][ni] = __builtin_amdgcn_mfma_f32_16x16x32_bf16(af[mi], bw[ni], acc[mi][ni], 0, 0, 0);
    }
    __syncthreads();
  }

  int rbase = m0 + wr * 64 + kg * 4;
#pragma unroll
  for (int mi = 0; mi < 4; ++mi) {
#pragma unroll
    for (int r = 0; r < 4; ++r) {
      int g = rbase + mi * 16 + r;
      int wi2 = g / 65;
      int n = g - wi2 * 65;
      size_t dstrow;
      if (n == 0) {
        dstrow = (size_t)(16777216 >> 8) + wi2;         // gt_out row
      } else {
        int s = n - 1;
        int b = wi2 >> 8, wh = (wi2 >> 4) & 15, ww = wi2 & 15;
        int r2 = s >> 3, cc = s & 7;
        dstrow = (size_t)(b << 14) + (wh * 8 + r2) * 128 + ww * 8 + cc;
      }
      float* dst = out + dstrow * 256;
#pragma unroll
      for (int ni = 0; ni < 4; ++ni) {
        int col = n0 + wc * 64 + ni * 16 + lm;
        dst[col] = acc[mi][ni][r] + bias[col];
      }
    }
  }
}

// ---------------------------------------------------------------- conv build (tap-serial, all-static)
__device__ __forceinline__ f32x8 row_lerp(const char* srcS, int row, int cg, float ty) {
  int a0 = row * 512 + ((cg * 16) ^ ((row & 7) << 4));
  int a1 = (row + 8) * 512 + ((cg * 16) ^ ((row & 7) << 4));
  bf16x8 a = *(const bf16x8*)(srcS + a0);
  bf16x8 b = *(const bf16x8*)(srcS + a1);
  f32x8 h;
#pragma unroll
  for (int e = 0; e < 8; ++e) {
    float av = bf2f((ushort)a[e]);
    h[e] = av + ty * (bf2f((ushort)b[e]) - av);
  }
  return h;
}
__device__ __forceinline__ void emit_u(char* U, const f32x8& Ha, const f32x8& Hb,
                                       float tx, int s, int cg) {
  bf16x8 o8;
#pragma unroll
  for (int e = 0; e < 8; ++e) {
    float lv = Ha[e];
    o8[e] = (short)f2bf(lv + tx * (Hb[e] - lv));
  }
  *(bf16x8*)(U + s * 512 + ((cg * 16) ^ ((s & 7) << 4))) = o8;
}

template<int XH, int DX>
__device__ __forceinline__ void conv_build(const char* srcS, char* U,
                                           int dy, int i, int cg)
{
  int yy = 2 * i + dy;
  float py = yy * (7.0f / 15.0f);
  int iy = (int)py; if (iy > 6) iy = 6;
  float ty = py - iy;
  constexpr int j0 = XH * 3;
  int rb = iy * 8 + j0;
  f32x8 H0 = row_lerp(srcS, rb + 0, cg, ty);
  f32x8 H1 = row_lerp(srcS, rb + 1, cg, ty);
  f32x8 H2 = row_lerp(srcS, rb + 2, cg, ty);
  f32x8 H3 = row_lerp(srcS, rb + 3, cg, ty);
  f32x8 H4 = row_lerp(srcS, rb + 4, cg, ty);
  int sb = i * 8 + XH * 4;
  if (XH == 0 && DX == 0) {
    emit_u(U, H0, H1, 0.0f,        sb + 0, cg);
    emit_u(U, H0, H1, 14.f / 15.f, sb + 1, cg);
    emit_u(U, H1, H2, 13.f / 15.f, sb + 2, cg);
    emit_u(U, H2, H3, 12.f / 15.f, sb + 3, cg);
  } else if (XH == 0 && DX == 1) {
    emit_u(U, H0, H1,  7.f / 15.f, sb + 0, cg);
    emit_u(U, H1, H2,  6.f / 15.f, sb + 1, cg);
    emit_u(U, H2, H3,  5.f / 15.f, sb + 2, cg);
    emit_u(U, H3, H4,  4.f / 15.f, sb + 3, cg);
  } else if (XH == 1 && DX == 0) {
    emit_u(U, H0, H1, 11.f / 15.f, sb + 0, cg);
    emit_u(U, H1, H2, 10.f / 15.f, sb + 1, cg);
    emit_u(U, H2, H3,  9.f / 15.f, sb + 2, cg);
    emit_u(U, H3, H4,  8.f / 15.f, sb + 3, cg);
  } else {
    emit_u(U, H1, H2,  3.f / 15.f, sb + 0, cg);
    emit_u(U, H2, H3,  2.f / 15.f, sb + 1, cg);
    emit_u(U, H3, H4,  1.f / 15.f, sb + 2, cg);
    emit_u(U, H3, H4,  1.0f,       sb + 3, cg);
  }
}

// ---------------------------------------------------------------- conv body (r11-clean, 512 threads)
__device__ void conv_body(int wi, const ushort* __restrict__ xc,
    const ushort* __restrict__ wconv, ushort* __restrict__ cconv, char* smem)
{
  ushort* srcS = (ushort*)smem;            // 32KB staged src (swizzled)
  ushort* Ubuf = (ushort*)(smem + 32768);  // 32KB one tap's U
  int tid = threadIdx.x, wave = tid >> 6, lane = tid & 63;
  int lm = lane & 15, kg = lane >> 4;

  const char* src_g = (const char*)(xc + (size_t)(wi * 65 + 1) * 256);
#pragma unroll
  for (int j = 0; j < 4; ++j) {
    int c = j * 512 + tid;
    int row = c >> 5, slot = c & 31;
    int srcoff = row * 512 + ((slot * 16) ^ ((row & 7) << 4));
    gl16(src_g + srcoff, (const ushort*)((const char*)srcS + c * 16));
  }

  f32x4 acc[4][2];
  f32x4 zero = {0.f, 0.f, 0.f, 0.f};
#pragma unroll
  for (int a = 0; a < 4; a++)
#pragma unroll
    for (int b = 0; b < 2; b++) acc[a][b] = zero;

  int cg = tid & 31;
  int i = (tid >> 5) & 7;
  int xh = tid >> 8;

  auto mfma_tap = [&](int t) {
    const ushort* wc = wconv + t * 256;
    for (int kk = 0; kk < 256; kk += 32) {
      int kb = kk + kg * 8;
      bf16x8 afr[4];
#pragma unroll
      for (int mi = 0; mi < 4; mi++) {
        int srow = mi * 16 + lm;
        int off = (srow * 512 + 2 * kb) ^ ((srow & 7) << 4);
        afr[mi] = *(const bf16x8*)((const char*)Ubuf + off);
      }
#pragma unroll
      for (int ni = 0; ni < 2; ni++) {
        bf16x8 b = *(const bf16x8*)(wc + (size_t)(wave * 32 + ni * 16 + lm) * 1024 + kb);
#pragma unroll
        for (int mi = 0; mi < 4; mi++)
          acc[mi][ni] = __builtin_amdgcn_mfma_f32_16x16x32_bf16(afr[mi], b, acc[mi][ni], 0, 0, 0);
      }
    }
  };

  __syncthreads();

  if (xh == 0) conv_build<0, 0>((const char*)srcS, (char*)Ubuf, 0, i, cg);
  else         conv_build<1, 0>((const char*)srcS, (char*)Ubuf, 0, i, cg);
  __syncthreads();
  mfma_tap(0);
  __syncthreads();
  if (xh == 0) conv_build<0, 1>((const char*)srcS, (char*)Ubuf, 0, i, cg);
  else         conv_build<1, 1>((const char*)srcS, (char*)Ubuf, 0, i, cg);
  __syncthreads();
  mfma_tap(1);
  __syncthreads();
  if (xh == 0) conv_build<0, 0>((const char*)srcS, (char*)Ubuf, 1, i, cg);
  else         conv_build<1, 0>((const char*)srcS, (char*)Ubuf, 1, i, cg);
  __syncthreads();
  mfma_tap(2);
  __syncthreads();
  if (xh == 0) conv_build<0, 1>((const char*)srcS, (char*)Ubuf, 1, i, cg);
  else         conv_build<1, 1>((const char*)srcS, (char*)Ubuf, 1, i, cg);
  __syncthreads();
  mfma_tap(3);

#pragma unroll
  for (int mi = 0; mi < 4; mi++) {
    int row = wi * 64 + mi * 16 + kg * 4;
#pragma unroll
    for (int ni = 0; ni < 2; ni++) {
      int col = wave * 32 + ni * 16 + lm;
#pragma unroll
      for (int r = 0; r < 4; r++)
        cconv[(size_t)(row + r) * 256 + col] = f2bf(acc[mi][ni][r]);
    }
  }
}

// ---------------------------------------------------------------- Q-GEMM body (512 threads, 128x128 tile)
__device__ void gemmq_body(int idx, const ushort* __restrict__ A,
    const ushort* __restrict__ W, const float* __restrict__ bias,
    ushort* __restrict__ C, char* smem)
{
  constexpr int K = 256, N = 256;
  ushort* As = (ushort*)smem;              // [2][128*64] = 32KB
  ushort* Bs = (ushort*)(smem + 32768);    // [2][128*64] = 32KB
  int gx = idx & 1, gy = idx >> 1;         // 2 n-blocks x 520 m-blocks
  int m0 = gy * 128, n0 = gx * 128;
  int tid = threadIdx.x, lane = tid & 63, wave = tid >> 6;
  int lm = lane & 15, kg = lane >> 4;
  int wr = wave >> 2, wc = wave & 3;       // 2x4 wave grid; wave tile = 64 rows x 32 cols

  const char* Ab = (const char*)A + (size_t)m0 * (K * 2);
  const char* Bb = (const char*)W + (size_t)n0 * (K * 2);

  auto stage = [&](int buf, int kt) {
#pragma unroll
    for (int j = 0; j < 2; ++j) {
      int c = j * 512 + tid;               // chunk 0..1023
      int row = c >> 3, slot = c & 7;
      int srcoff = row * (K * 2) + kt * 128 + ((slot * 16) ^ ((row & 7) << 4));
      gl16(Ab + srcoff, (const ushort*)((const char*)As + buf * 16384 + c * 16));
      gl16(Bb + srcoff, (const ushort*)((const char*)Bs + buf * 16384 + c * 16));
    }
  };

  f32x4 acc[4][2];
  f32x4 zero = {0.f, 0.f, 0.f, 0.f};
#pragma unroll
  for (int a = 0; a < 4; ++a)
#pragma unroll
    for (int b = 0; b < 2; ++b) acc[a][b] = zero;

  stage(0, 0);
  __syncthreads();
#pragma unroll
  for (int t = 0; t < 4; ++t) {
    int cur = t & 1;
    if (t < 3) stage(cur ^ 1, t + 1);
#pragma unroll
    for (int s = 0; s < 2; ++s) {
      int sw = (lm & 7) << 4;
      bf16x8 af[4], bw[2];
#pragma unroll
      for (int mi = 0; mi < 4; ++mi) {
        int row = wr * 64 + mi * 16 + lm;
        af[mi] = *(const bf16x8*)((const char*)As + cur * 16384 + row * 128 + ((s * 64 + kg * 16) ^ sw));
      }
#pragma unroll
      for (int ni = 0; ni < 2; ++ni) {
        int row = wc * 32 + ni * 16 + lm;
        bw[ni] = *(const bf16x8*)((const char*)Bs + cur * 16384 + row * 128 + ((s * 64 + kg * 16) ^ sw));
      }
#pragma unroll
      for (int mi = 0; mi < 4; ++mi)
#pragma unroll
        for (int ni = 0; ni < 2; ++ni)
          acc[mi][ni] = __builtin_amdgcn_mfma_f32_16x16x32_bf16(af[mi], bw[ni], acc[mi][ni], 0, 0, 0);
    }
    __syncthreads();
  }

  int rbase = m0 + wr * 64 + kg * 4;
#pragma unroll
  for (int ni = 0; ni < 2; ++ni) {
    int col = n0 + wc * 32 + ni * 16 + lm;
    float bv = bias[col];
#pragma unroll
    for (int mi = 0; mi < 4; ++mi) {
#pragma unroll
      for (int r = 0; r < 4; ++r)
        C[(size_t)(rbase + mi * 16 + r) * N + col] = f2bf(acc[mi][ni][r] + bv);
    }
  }
}

// ---------------------------------------------------------------- merged conv + Q-GEMM (role-split blocks)
__global__ __launch_bounds__(512)
__attribute__((amdgpu_waves_per_eu(4, 4)))
void k_cvq(const ushort* __restrict__ xc, const ushort* __restrict__ wconv,
    ushort* __restrict__ cconv, const ushort* __restrict__ wq,
    const float* __restrict__ qbias, ushort* __restrict__ qout)
{
  __shared__ __align__(16) char smem[65536];
  int b = blockIdx.x;                       // 0..2063
  if (b < 2048) {
    if ((b & 1) == 0) conv_body(b >> 1, xc, wconv, cconv, smem);
    else              gemmq_body(b >> 1, xc, wq, qbias, qout, smem);
  } else {
    gemmq_body(1024 + (b - 2048), xc, wq, qbias, qout, smem);
  }
}

// ---------------------------------------------------------------- bias + LayerNorm -> xkv rows 1..64
__global__ __launch_bounds__(256) void k_ln(const ushort* __restrict__ cconv,
    const float* __restrict__ srb, const float* __restrict__ nw,
    const float* __restrict__ nb, ushort* __restrict__ xkv)
{
  int row = blockIdx.x * 4 + (threadIdx.x >> 6);   // 0..65535
  int lane = threadIdx.x & 63;
  const ushort* p = cconv + (size_t)row * 256;
  float v[4]; float sum = 0.f, sq = 0.f;
#pragma unroll
  for (int r = 0; r < 4; r++) {
    int c = r * 64 + lane;
    v[r] = bf2f(p[c]) + srb[c];
    sum += v[r]; sq += v[r] * v[r];
  }
#pragma unroll
  for (int off = 1; off < 64; off <<= 1) {
    sum += __shfl_xor(sum, off, 64);
    sq  += __shfl_xor(sq,  off, 64);
  }
  float mean = sum * (1.f / 256.f);
  float var = sq * (1.f / 256.f) - mean * mean;
  float rs = rsqrtf(var + 1e-5f);
  int wi = row >> 6, s = row & 63;
  ushort* o = xkv + (size_t)(wi * 65 + 1 + s) * 256;
#pragma unroll
  for (int r = 0; r < 4; r++) {
    int c = r * 64 + lane;
    o[c] = f2bf((v[r] - mean) * rs * nw[c] + nb[c]);
  }
}

// ---------------------------------------------------------------- MFMA attention: one wave per (window, head)
__global__ __launch_bounds__(256) void k_attn(const ushort* __restrict__ q,
    const ushort* __restrict__ kv, ushort* __restrict__ att)
{
  __shared__ ushort smem[4][8064];           // per wave: P [80][72] + V^T [32][72]
  int wi = blockIdx.x >> 1;
  int tid = threadIdx.x, wave = tid >> 6, lane = tid & 63;
  int h = (blockIdx.x & 1) * 4 + wave;
  int lm = lane & 15, kg = lane >> 4;
  ushort* plds = smem[wave];                 // [80][72] bf16 P (later reused for O)
  ushort* vt   = smem[wave] + 5760;          // [32][72] bf16 V^T

  size_t qbase  = (size_t)wi * 65 * 256 + (size_t)h * 32;
  size_t kvbase = (size_t)wi * 65 * 512 + (size_t)h * 32;

  for (int e = lane; e < 2080; e += 64) {
    int m = e >> 5, d = e & 31;
    vt[d * 72 + m] = kv[kvbase + (size_t)m * 512 + 256 + d];
  }

  bf16x8 akf[5], bqf[5];
#pragma unroll
  for (int i = 0; i < 5; i++) {
    akf[i] = *(const bf16x8*)(kv + kvbase + (size_t)(16 * i + lm) * 512 + kg * 8);
    bqf[i] = *(const bf16x8*)(q  + qbase  + (size_t)(16 * i + lm) * 256 + kg * 8);
  }

  f32x4 sc[5][5];
  f32x4 zero = {0.f, 0.f, 0.f, 0.f};
#pragma unroll
  for (int mi = 0; mi < 5; mi++)
#pragma unroll
    for (int nj = 0; nj < 5; nj++) sc[mi][nj] = zero;
#pragma unroll
  for (int mi = 0; mi < 5; mi++)
#pragma unroll
    for (int nj = 0; nj < 5; nj++)
      sc[mi][nj] = __builtin_amdgcn_mfma_f32_16x16x32_bf16(akf[mi], bqf[nj], sc[mi][nj], 0, 0, 0);

  const float C = SCALE_ * 1.4426950408889634f;   // scale * log2(e)
  float inv[5], p64b[5];
#pragma unroll
  for (int nj = 0; nj < 5; nj++) {
    float s4 = sc[4][nj][0];                      // m = 64+4*kg; valid only kg==0
    float mx = (kg == 0) ? s4 : -1e30f;
#pragma unroll
    for (int mi = 0; mi < 4; mi++)
#pragma unroll
      for (int r = 0; r < 4; r++) mx = fmaxf(mx, sc[mi][nj][r]);
    mx = fmaxf(mx, __shfl_xor(mx, 16, 64));
    mx = fmaxf(mx, __shfl_xor(mx, 32, 64));
    float sum = 0.f;
#pragma unroll
    for (int mi = 0; mi < 4; mi++)
#pragma unroll
      for (int r = 0; r < 4; r++) {
        float e = exp2f((sc[mi][nj][r] - mx) * C);
        sc[mi][nj][r] = e; sum += e;
      }
    float e4 = exp2f((s4 - mx) * C);
    sum += (kg == 0) ? e4 : 0.f;
    sum += __shfl_xor(sum, 16, 64);
    sum += __shfl_xor(sum, 32, 64);
    inv[nj] = 1.0f / sum;
    p64b[nj] = __shfl(e4, lm, 64);                // broadcast kg==0 value
  }

#pragma unroll
  for (int nj = 0; nj < 5; nj++) {
    int n = 16 * nj + lm;
#pragma unroll
    for (int mi = 0; mi < 4; mi++) {
      uint lo = (uint)f2bf(sc[mi][nj][0]) | ((uint)f2bf(sc[mi][nj][1]) << 16);
      uint hi = (uint)f2bf(sc[mi][nj][2]) | ((uint)f2bf(sc[mi][nj][3]) << 16);
      u32x2 pk = {lo, hi};
      *(u32x2*)(plds + n * 72 + 16 * mi + 4 * kg) = pk;
    }
  }

  f32x4 od[2][5];
#pragma unroll
  for (int dt = 0; dt < 2; dt++)
#pragma unroll
    for (int nj = 0; nj < 5; nj++) od[dt][nj] = zero;
#pragma unroll
  for (int c = 0; c < 2; c++) {
    bf16x8 av[2], bp[5];
#pragma unroll
    for (int dt = 0; dt < 2; dt++)
      av[dt] = *(const bf16x8*)(vt + (16 * dt + lm) * 72 + c * 32 + kg * 8);
#pragma unroll
    for (int nj = 0; nj < 5; nj++)
      bp[nj] = *(const bf16x8*)(plds + (16 * nj + lm) * 72 + c * 32 + kg * 8);
#pragma unroll
    for (int dt = 0; dt < 2; dt++)
#pragma unroll
      for (int nj = 0; nj < 5; nj++)
        od[dt][nj] = __builtin_amdgcn_mfma_f32_16x16x32_bf16(av[dt], bp[nj], od[dt][nj], 0, 0, 0);
  }
  float v64[8];
#pragma unroll
  for (int dt = 0; dt < 2; dt++)
#pragma unroll
    for (int r = 0; r < 4; r++)
      v64[dt * 4 + r] = bf2f(vt[(16 * dt + 4 * kg + r) * 72 + 64]);
#pragma unroll
  for (int dt = 0; dt < 2; dt++)
#pragma unroll
    for (int nj = 0; nj < 5; nj++)
#pragma unroll
      for (int r = 0; r < 4; r++)
        od[dt][nj][r] += v64[dt * 4 + r] * p64b[nj];

#pragma unroll
  for (int nj = 0; nj < 5; nj++) {
    int n = 16 * nj + lm;
    float scl = inv[nj];
#pragma unroll
    for (int dt = 0; dt < 2; dt++) {
      uint lo = (uint)f2bf(od[dt][nj][0] * scl) | ((uint)f2bf(od[dt][nj][1] * scl) << 16);
      uint hi = (uint)f2bf(od[dt][nj][2] * scl) | ((uint)f2bf(od[dt][nj][3] * scl) << 16);
      u32x2 pk = {lo, hi};
      *(u32x2*)(plds + n * 40 + 16 * dt + 4 * kg) = pk;
    }
  }
  size_t abase = (size_t)wi * 65 * 256 + (size_t)h * 32;
  for (int e = lane; e < 1040; e += 64) {
    int n = e >> 4, d2 = e & 15;
    *(uint*)(att + abase + (size_t)n * 256 + 2 * d2) = *(const uint*)(plds + n * 40 + 2 * d2);
  }
}

// ---------------------------------------------------------------- launch
extern "C" void kernel_launch(void* const* d_in, const int* in_sizes, int n_in,
                              void* d_out, int out_size, void* d_ws, size_t ws_size,
                              hipStream_t stream)
{
  const float* x    = (const float*)d_in[0];
  const float* gt   = (const float*)d_in[1];
  const float* q_w  = (const float*)d_in[2];
  const float* q_b  = (const float*)d_in[3];
  const float* kv_w = (const float*)d_in[4];
  const float* kv_b = (const float*)d_in[5];
  const float* sr_w = (const float*)d_in[6];
  const float* sr_b = (const float*)d_in[7];
  const float* nw   = (const float*)d_in[8];
  const float* nb   = (const float*)d_in[9];
  const float* p_w  = (const float*)d_in[10];
  const float* p_b  = (const float*)d_in[11];
  (void)in_sizes; (void)n_in; (void)out_size;

  if (ws_size < 204996608u) return;
  char* ws = (char*)d_ws;
  ushort* xc  = (ushort*)(ws);              // 34,078,720  (reused as att out)
  ushort* qb  = (ushort*)(ws + 34078720);   // 34,078,720  (Q-proj output)
  ushort* xkv = (ushort*)(ws + 68157440);   // 34,078,720
  ushort* kv  = (ushort*)(ws + 102236160);  // 68,157,440
  ushort* ccv = (ushort*)(ws + 170393600);  // 33,554,432
  ushort* wq  = (ushort*)(ws + 203948032);  // 131,072
  ushort* wkv = (ushort*)(ws + 204079104);  // 262,144
  ushort* wpr = (ushort*)(ws + 204341248);  // 131,072
  ushort* wcv = (ushort*)(ws + 204472320);  // 524,288

  float* out = (float*)d_out;
  float* out2 = out + 16777216 + 262144;    // skip

  k_prep<<<68608, 256, 0, stream>>>(x, gt, q_w, kv_w, p_w, sr_w,
                                    xc, xkv, out2, wq, wkv, wpr, wcv);
  k_cvq<<<2064, 512, 0, stream>>>(xc, wcv, ccv, wq, q_b, qb);
  k_ln<<<16384, 256, 0, stream>>>(ccv, sr_b, nw, nb, xkv);
  k_gemm2<512><<<dim3(4, 520), 256, 0, stream>>>(xkv, wkv, kv_b, kv);
  k_attn<<<2048, 256, 0, stream>>>(qb, kv, xc);
  k_gemm_out<<<dim3(2, 520), 256, 0, stream>>>(xc, wpr, p_b, out);
}

// Round 13
// 240.152 us; speedup vs baseline: 1.2966x; 1.2966x over previous
//
#include <hip/hip_runtime.h>

typedef __attribute__((ext_vector_type(4))) float f32x4;
typedef __attribute__((ext_vector_type(8))) float f32x8;
typedef __attribute__((ext_vector_type(8))) short bf16x8;
typedef __attribute__((ext_vector_type(2))) uint u32x2;

#define SCALE_ 0.17677669529663687f

__device__ __forceinline__ float bf2f(ushort u){
  union { unsigned i; float f; } v; v.i = ((unsigned)u) << 16; return v.f;
}
__device__ __forceinline__ ushort f2bf(float f){
  union { float f; unsigned i; } v; v.f = f;
  unsigned r = v.i + 0x7fffu + ((v.i >> 16) & 1u);
  return (ushort)(r >> 16);
}
__device__ __forceinline__ void gl16(const void* g, const ushort* l) {
  __builtin_amdgcn_global_load_lds((const __attribute__((address_space(1))) uint*)g,
                                   (__attribute__((address_space(3))) uint*)l, 16, 0, 0);
}

// ---------------------------------------------------------------- prep (float4-vectorized) + wprep tail
__global__ __launch_bounds__(256) void k_prep(const float* __restrict__ x,
    const float* __restrict__ gt, const float* __restrict__ qw,
    const float* __restrict__ kvw, const float* __restrict__ pw,
    const float* __restrict__ srw, ushort* __restrict__ xc,
    ushort* __restrict__ xkv, float* __restrict__ out2,
    ushort* __restrict__ wq, ushort* __restrict__ wkv,
    ushort* __restrict__ wpr, ushort* __restrict__ wcv)
{
  int blk = blockIdx.x;
  int tid = threadIdx.x;
  if (blk >= 16640) {                       // wprep role
    int i = (blk - 16640) * 256 + tid;      // 0..524287
    if (i < 65536)            wq[i] = f2bf(qw[i]);
    else if (i < 196608)      wkv[i - 65536] = f2bf(kvw[i - 65536]);
    else if (i < 262144)      wpr[i - 196608] = f2bf(pw[i - 196608]);
    else {
      int j = i - 262144;
      int o = j >> 10, t = (j >> 8) & 3, cc = j & 255;
      wcv[j] = f2bf(srw[o * 1024 + cc * 4 + t]);
    }
    return;
  }
  int row = blk * 4 + (tid >> 6);           // 0..66559
  int c4 = (tid & 63) * 4;
  int wi = row / 65, n = row - wi * 65;
  if (n == 0) {
    float4 g4 = *(const float4*)(gt + (size_t)wi * 256 + c4);
    uint lo = (uint)f2bf(g4.x) | ((uint)f2bf(g4.y) << 16);
    uint hi = (uint)f2bf(g4.z) | ((uint)f2bf(g4.w) << 16);
    u32x2 pk = {lo, hi};
    *(u32x2*)(xc  + (size_t)row * 256 + c4) = pk;
    *(u32x2*)(xkv + (size_t)row * 256 + c4) = pk;
    *(float4*)(out2 + (size_t)wi * 256 + c4) = g4;
  } else {
    int s = n - 1, r = s >> 3, cc = s & 7;
    int b = wi >> 8, wh = (wi >> 4) & 15, ww = wi & 15;
    int hw = (wh * 8 + r) * 128 + ww * 8 + cc;
    float4 v4 = *(const float4*)(x + ((size_t)b * 16384 + hw) * 256 + c4);
    uint lo = (uint)f2bf(v4.x) | ((uint)f2bf(v4.y) << 16);
    uint hi = (uint)f2bf(v4.z) | ((uint)f2bf(v4.w) << 16);
    u32x2 pk = {lo, hi};
    *(u32x2*)(xc + (size_t)row * 256 + c4) = pk;
  }
}

// ---------------------------------------------------------------- tiled GEMM (m97 structure + XCD swizzle)
template<int N>
__global__ __launch_bounds__(256) void k_gemm2(const ushort* __restrict__ A,
    const ushort* __restrict__ W, const float* __restrict__ bias,
    ushort* __restrict__ C)
{
  constexpr int K = 256;
  __shared__ __align__(16) ushort As[2][128 * 64];
  __shared__ __align__(16) ushort Bs[2][128 * 64];
  int lin = blockIdx.y * gridDim.x + blockIdx.x;
  int qq = (gridDim.x * gridDim.y) >> 3;
  int sw2 = (lin & 7) * qq + (lin >> 3);
  int m0 = (sw2 / gridDim.x) * 128, n0 = (sw2 % gridDim.x) * 128;
  int tid = threadIdx.x, lane = tid & 63;
  int wave = tid >> 6;
  int lm = lane & 15, kg = lane >> 4;
  int wr = wave >> 1, wc = wave & 1;

  const char* Ab = (const char*)A + (size_t)m0 * (K * 2);
  const char* Bb = (const char*)W + (size_t)n0 * (K * 2);

  auto stage = [&](int buf, int kt) {
#pragma unroll
    for (int j = 0; j < 4; ++j) {
      int c = j * 256 + tid;            // chunk 0..1023
      int row = c >> 3, slot = c & 7;   // 8 x 16B per 128B row
      int srcoff = row * (K * 2) + kt * 128 + ((slot * 16) ^ ((row & 7) << 4));
      gl16(Ab + srcoff, (const ushort*)((const char*)As[buf] + c * 16));
      gl16(Bb + srcoff, (const ushort*)((const char*)Bs[buf] + c * 16));
    }
  };

  f32x4 acc[4][4];
  f32x4 zero = {0.f, 0.f, 0.f, 0.f};
#pragma unroll
  for (int a = 0; a < 4; ++a)
#pragma unroll
    for (int b = 0; b < 4; ++b) acc[a][b] = zero;

  stage(0, 0);
  __syncthreads();
#pragma unroll
  for (int t = 0; t < 4; ++t) {
    int cur = t & 1;
    if (t < 3) stage(cur ^ 1, t + 1);
#pragma unroll
    for (int s = 0; s < 2; ++s) {
      int sw = (lm & 7) << 4;
      bf16x8 af[4], bw[4];
#pragma unroll
      for (int mi = 0; mi < 4; ++mi) {
        int row = wr * 64 + mi * 16 + lm;
        af[mi] = *(const bf16x8*)((const char*)As[cur] + row * 128 + ((s * 64 + kg * 16) ^ sw));
      }
#pragma unroll
      for (int ni = 0; ni < 4; ++ni) {
        int row = wc * 64 + ni * 16 + lm;
        bw[ni] = *(const bf16x8*)((const char*)Bs[cur] + row * 128 + ((s * 64 + kg * 16) ^ sw));
      }
#pragma unroll
      for (int mi = 0; mi < 4; ++mi)
#pragma unroll
        for (int ni = 0; ni < 4; ++ni)
          acc[mi][ni] = __builtin_amdgcn_mfma_f32_16x16x32_bf16(af[mi], bw[ni], acc[mi][ni], 0, 0, 0);
    }
    __syncthreads();
  }

  int rbase = m0 + wr * 64 + kg * 4;
#pragma unroll
  for (int ni = 0; ni < 4; ++ni) {
    int col = n0 + wc * 64 + ni * 16 + lm;
    float bv = bias[col];
#pragma unroll
    for (int mi = 0; mi < 4; ++mi) {
#pragma unroll
      for (int r = 0; r < 4; ++r)
        C[(size_t)(rbase + mi * 16 + r) * N + col] = f2bf(acc[mi][ni][r] + bv);
    }
  }
}

// ---------------------------------------------------------------- proj GEMM with fused scatter epilogue
__global__ __launch_bounds__(256) void k_gemm_out(const ushort* __restrict__ A,
    const ushort* __restrict__ W, const float* __restrict__ bias,
    float* __restrict__ out)
{
  constexpr int K = 256;
  __shared__ __align__(16) ushort As[2][128 * 64];
  __shared__ __align__(16) ushort Bs[2][128 * 64];
  int lin = blockIdx.y * gridDim.x + blockIdx.x;
  int qq = (gridDim.x * gridDim.y) >> 3;
  int sw2 = (lin & 7) * qq + (lin >> 3);
  int m0 = (sw2 / gridDim.x) * 128, n0 = (sw2 % gridDim.x) * 128;
  int tid = threadIdx.x, lane = tid & 63;
  int wave = tid >> 6;
  int lm = lane & 15, kg = lane >> 4;
  int wr = wave >> 1, wc = wave & 1;

  const char* Ab = (const char*)A + (size_t)m0 * (K * 2);
  const char* Bb = (const char*)W + (size_t)n0 * (K * 2);

  auto stage = [&](int buf, int kt) {
#pragma unroll
    for (int j = 0; j < 4; ++j) {
      int c = j * 256 + tid;
      int row = c >> 3, slot = c & 7;
      int srcoff = row * (K * 2) + kt * 128 + ((slot * 16) ^ ((row & 7) << 4));
      gl16(Ab + srcoff, (const ushort*)((const char*)As[buf] + c * 16));
      gl16(Bb + srcoff, (const ushort*)((const char*)Bs[buf] + c * 16));
    }
  };

  f32x4 acc[4][4];
  f32x4 zero = {0.f, 0.f, 0.f, 0.f};
#pragma unroll
  for (int a = 0; a < 4; ++a)
#pragma unroll
    for (int b = 0; b < 4; ++b) acc[a][b] = zero;

  stage(0, 0);
  __syncthreads();
#pragma unroll
  for (int t = 0; t < 4; ++t) {
    int cur = t & 1;
    if (t < 3) stage(cur ^ 1, t + 1);
#pragma unroll
    for (int s = 0; s < 2; ++s) {
      int sw = (lm & 7) << 4;
      bf16x8 af[4], bw[4];
#pragma unroll
      for (int mi = 0; mi < 4; ++mi) {
        int row = wr * 64 + mi * 16 + lm;
        af[mi] = *(const bf16x8*)((const char*)As[cur] + row * 128 + ((s * 64 + kg * 16) ^ sw));
      }
#pragma unroll
      for (int ni = 0; ni < 4; ++ni) {
        int row = wc * 64 + ni * 16 + lm;
        bw[ni] = *(const bf16x8*)((const char*)Bs[cur] + row * 128 + ((s * 64 + kg * 16) ^ sw));
      }
#pragma unroll
      for (int mi = 0; mi < 4; ++mi)
#pragma unroll
        for (int ni = 0; ni < 4; ++ni)
          acc[mi][ni] = __builtin_amdgcn_mfma_f32_16x16x32_bf16(af[mi], bw[ni], acc[mi][ni], 0, 0, 0);
    }
    __syncthreads();
  }

  int rbase = m0 + wr * 64 + kg * 4;
#pragma unroll
  for (int mi = 0; mi < 4; ++mi) {
#pragma unroll
    for (int r = 0; r < 4; ++r) {
      int g = rbase + mi * 16 + r;
      int wi2 = g / 65;
      int n = g - wi2 * 65;
      size_t dstrow;
      if (n == 0) {
        dstrow = (size_t)(16777216 >> 8) + wi2;         // gt_out row
      } else {
        int s = n - 1;
        int b = wi2 >> 8, wh = (wi2 >> 4) & 15, ww = wi2 & 15;
        int r2 = s >> 3, cc = s & 7;
        dstrow = (size_t)(b << 14) + (wh * 8 + r2) * 128 + ww * 8 + cc;
      }
      float* dst = out + dstrow * 256;
#pragma unroll
      for (int ni = 0; ni < 4; ++ni) {
        int col = n0 + wc * 64 + ni * 16 + lm;
        dst[col] = acc[mi][ni][r] + bias[col];
      }
    }
  }
}

// ---------------------------------------------------------------- SR conv (r6 proven version): 512 threads,
// double-buffered U, 1 barrier per tap; wave owns 64s x 32o; build spread over 16 groups.
__global__ __launch_bounds__(512) void k_conv(const ushort* __restrict__ xc,
    const ushort* __restrict__ wconv, ushort* __restrict__ cconv)
{
  __shared__ ushort U[2][64 * 256];
  int wi = blockIdx.x;
  int tid = threadIdx.x, wave = tid >> 6, lane = tid & 63;
  int lm = lane & 15, kg = lane >> 4;
  const ushort* src = xc + (size_t)(wi * 65 + 1) * 256;
  f32x4 acc[4][2];
  f32x4 zero = {0.f, 0.f, 0.f, 0.f};
#pragma unroll
  for (int a = 0; a < 4; a++)
#pragma unroll
    for (int b = 0; b < 2; b++) acc[a][b] = zero;

  int cb = (tid & 31) * 8;   // channel block (8 ch)
  int sg = tid >> 5;         // spatial group 0..15

  auto build = [&](int t, ushort* Ub) {
    int dy = t >> 1, dx = t & 1;
    for (int s = sg; s < 64; s += 16) {
      int i = s >> 3, j = s & 7;
      int yy = 2 * i + dy, xx = 2 * j + dx;
      float py = yy * (7.0f / 15.0f); int iy = (int)py; if (iy > 6) iy = 6; float ty = py - iy;
      float px = xx * (7.0f / 15.0f); int ix = (int)px; if (ix > 6) ix = 6; float tx = px - ix;
      float w00 = (1.f - ty) * (1.f - tx), w01 = (1.f - ty) * tx;
      float w10 = ty * (1.f - tx), w11 = ty * tx;
      const ushort* p = src + (size_t)(iy * 8 + ix) * 256 + cb;
      bf16x8 p00 = *(const bf16x8*)(p);
      bf16x8 p01 = *(const bf16x8*)(p + 256);
      bf16x8 p10 = *(const bf16x8*)(p + 2048);
      bf16x8 p11 = *(const bf16x8*)(p + 2304);
      bf16x8 o8;
#pragma unroll
      for (int jj = 0; jj < 8; jj++) {
        float v = w00 * bf2f((ushort)p00[jj]) + w01 * bf2f((ushort)p01[jj])
                + w10 * bf2f((ushort)p10[jj]) + w11 * bf2f((ushort)p11[jj]);
        o8[jj] = (short)f2bf(v);
      }
      int byteoff = s * 512 + ((2 * cb) ^ ((s & 7) << 4));
      *(bf16x8*)((char*)Ub + byteoff) = o8;
    }
  };

  build(0, U[0]);
  __syncthreads();
  for (int t = 0; t < 4; t++) {
    const ushort* Ub = U[t & 1];
    const ushort* wc = wconv + t * 256;
    for (int kk = 0; kk < 256; kk += 32) {
      int kb = kk + kg * 8;
      bf16x8 afr[4];
#pragma unroll
      for (int mi = 0; mi < 4; mi++) {
        int srow = mi * 16 + lm;
        int off = (srow * 512 + 2 * kb) ^ ((srow & 7) << 4);
        afr[mi] = *(const bf16x8*)((const char*)Ub + off);
      }
#pragma unroll
      for (int ni = 0; ni < 2; ni++) {
        bf16x8 b = *(const bf16x8*)(wc + (size_t)(wave * 32 + ni * 16 + lm) * 1024 + kb);
#pragma unroll
        for (int mi = 0; mi < 4; mi++)
          acc[mi][ni] = __builtin_amdgcn_mfma_f32_16x16x32_bf16(afr[mi], b, acc[mi][ni], 0, 0, 0);
      }
    }
    if (t < 3) build(t + 1, U[(t + 1) & 1]);
    __syncthreads();
  }

#pragma unroll
  for (int mi = 0; mi < 4; mi++) {
    int row = wi * 64 + mi * 16 + kg * 4;
#pragma unroll
    for (int ni = 0; ni < 2; ni++) {
      int col = wave * 32 + ni * 16 + lm;
#pragma unroll
      for (int r = 0; r < 4; r++)
        cconv[(size_t)(row + r) * 256 + col] = f2bf(acc[mi][ni][r]);
    }
  }
}

// ---------------------------------------------------------------- bias + LayerNorm -> xkv rows 1..64
__global__ __launch_bounds__(256) void k_ln(const ushort* __restrict__ cconv,
    const float* __restrict__ srb, const float* __restrict__ nw,
    const float* __restrict__ nb, ushort* __restrict__ xkv)
{
  int row = blockIdx.x * 4 + (threadIdx.x >> 6);   // 0..65535
  int lane = threadIdx.x & 63;
  const ushort* p = cconv + (size_t)row * 256;
  float v[4]; float sum = 0.f, sq = 0.f;
#pragma unroll
  for (int r = 0; r < 4; r++) {
    int c = r * 64 + lane;
    v[r] = bf2f(p[c]) + srb[c];
    sum += v[r]; sq += v[r] * v[r];
  }
#pragma unroll
  for (int off = 1; off < 64; off <<= 1) {
    sum += __shfl_xor(sum, off, 64);
    sq  += __shfl_xor(sq,  off, 64);
  }
  float mean = sum * (1.f / 256.f);
  float var = sq * (1.f / 256.f) - mean * mean;
  float rs = rsqrtf(var + 1e-5f);
  int wi = row >> 6, s = row & 63;
  ushort* o = xkv + (size_t)(wi * 65 + 1 + s) * 256;
#pragma unroll
  for (int r = 0; r < 4; r++) {
    int c = r * 64 + lane;
    o[c] = f2bf((v[r] - mean) * rs * nw[c] + nb[c]);
  }
}

// ---------------------------------------------------------------- MFMA attention: one wave per (window, head)
__global__ __launch_bounds__(256) void k_attn(const ushort* __restrict__ q,
    const ushort* __restrict__ kv, ushort* __restrict__ att)
{
  __shared__ ushort smem[4][8064];           // per wave: P [80][72] + V^T [32][72]
  int wi = blockIdx.x >> 1;
  int tid = threadIdx.x, wave = tid >> 6, lane = tid & 63;
  int h = (blockIdx.x & 1) * 4 + wave;
  int lm = lane & 15, kg = lane >> 4;
  ushort* plds = smem[wave];                 // [80][72] bf16 P (later reused for O)
  ushort* vt   = smem[wave] + 5760;          // [32][72] bf16 V^T

  size_t qbase  = (size_t)wi * 65 * 256 + (size_t)h * 32;
  size_t kvbase = (size_t)wi * 65 * 512 + (size_t)h * 32;

  for (int e = lane; e < 2080; e += 64) {
    int m = e >> 5, d = e & 31;
    vt[d * 72 + m] = kv[kvbase + (size_t)m * 512 + 256 + d];
  }

  bf16x8 akf[5], bqf[5];
#pragma unroll
  for (int i = 0; i < 5; i++) {
    akf[i] = *(const bf16x8*)(kv + kvbase + (size_t)(16 * i + lm) * 512 + kg * 8);
    bqf[i] = *(const bf16x8*)(q  + qbase  + (size_t)(16 * i + lm) * 256 + kg * 8);
  }

  f32x4 sc[5][5];
  f32x4 zero = {0.f, 0.f, 0.f, 0.f};
#pragma unroll
  for (int mi = 0; mi < 5; mi++)
#pragma unroll
    for (int nj = 0; nj < 5; nj++) sc[mi][nj] = zero;
#pragma unroll
  for (int mi = 0; mi < 5; mi++)
#pragma unroll
    for (int nj = 0; nj < 5; nj++)
      sc[mi][nj] = __builtin_amdgcn_mfma_f32_16x16x32_bf16(akf[mi], bqf[nj], sc[mi][nj], 0, 0, 0);

  const float C = SCALE_ * 1.4426950408889634f;   // scale * log2(e)
  float inv[5], p64b[5];
#pragma unroll
  for (int nj = 0; nj < 5; nj++) {
    float s4 = sc[4][nj][0];                      // m = 64+4*kg; valid only kg==0
    float mx = (kg == 0) ? s4 : -1e30f;
#pragma unroll
    for (int mi = 0; mi < 4; mi++)
#pragma unroll
      for (int r = 0; r < 4; r++) mx = fmaxf(mx, sc[mi][nj][r]);
    mx = fmaxf(mx, __shfl_xor(mx, 16, 64));
    mx = fmaxf(mx, __shfl_xor(mx, 32, 64));
    float sum = 0.f;
#pragma unroll
    for (int mi = 0; mi < 4; mi++)
#pragma unroll
      for (int r = 0; r < 4; r++) {
        float e = exp2f((sc[mi][nj][r] - mx) * C);
        sc[mi][nj][r] = e; sum += e;
      }
    float e4 = exp2f((s4 - mx) * C);
    sum += (kg == 0) ? e4 : 0.f;
    sum += __shfl_xor(sum, 16, 64);
    sum += __shfl_xor(sum, 32, 64);
    inv[nj] = 1.0f / sum;
    p64b[nj] = __shfl(e4, lm, 64);                // broadcast kg==0 value
  }

#pragma unroll
  for (int nj = 0; nj < 5; nj++) {
    int n = 16 * nj + lm;
#pragma unroll
    for (int mi = 0; mi < 4; mi++) {
      uint lo = (uint)f2bf(sc[mi][nj][0]) | ((uint)f2bf(sc[mi][nj][1]) << 16);
      uint hi = (uint)f2bf(sc[mi][nj][2]) | ((uint)f2bf(sc[mi][nj][3]) << 16);
      u32x2 pk = {lo, hi};
      *(u32x2*)(plds + n * 72 + 16 * mi + 4 * kg) = pk;
    }
  }

  f32x4 od[2][5];
#pragma unroll
  for (int dt = 0; dt < 2; dt++)
#pragma unroll
    for (int nj = 0; nj < 5; nj++) od[dt][nj] = zero;
#pragma unroll
  for (int c = 0; c < 2; c++) {
    bf16x8 av[2], bp[5];
#pragma unroll
    for (int dt = 0; dt < 2; dt++)
      av[dt] = *(const bf16x8*)(vt + (16 * dt + lm) * 72 + c * 32 + kg * 8);
#pragma unroll
    for (int nj = 0; nj < 5; nj++)
      bp[nj] = *(const bf16x8*)(plds + (16 * nj + lm) * 72 + c * 32 + kg * 8);
#pragma unroll
    for (int dt = 0; dt < 2; dt++)
#pragma unroll
      for (int nj = 0; nj < 5; nj++)
        od[dt][nj] = __builtin_amdgcn_mfma_f32_16x16x32_bf16(av[dt], bp[nj], od[dt][nj], 0, 0, 0);
  }
  float v64[8];
#pragma unroll
  for (int dt = 0; dt < 2; dt++)
#pragma unroll
    for (int r = 0; r < 4; r++)
      v64[dt * 4 + r] = bf2f(vt[(16 * dt + 4 * kg + r) * 72 + 64]);
#pragma unroll
  for (int dt = 0; dt < 2; dt++)
#pragma unroll
    for (int nj = 0; nj < 5; nj++)
#pragma unroll
      for (int r = 0; r < 4; r++)
        od[dt][nj][r] += v64[dt * 4 + r] * p64b[nj];

#pragma unroll
  for (int nj = 0; nj < 5; nj++) {
    int n = 16 * nj + lm;
    float scl = inv[nj];
#pragma unroll
    for (int dt = 0; dt < 2; dt++) {
      uint lo = (uint)f2bf(od[dt][nj][0] * scl) | ((uint)f2bf(od[dt][nj][1] * scl) << 16);
      uint hi = (uint)f2bf(od[dt][nj][2] * scl) | ((uint)f2bf(od[dt][nj][3] * scl) << 16);
      u32x2 pk = {lo, hi};
      *(u32x2*)(plds + n * 40 + 16 * dt + 4 * kg) = pk;
    }
  }
  size_t abase = (size_t)wi * 65 * 256 + (size_t)h * 32;
  for (int e = lane; e < 1040; e += 64) {
    int n = e >> 4, d2 = e & 15;
    *(uint*)(att + abase + (size_t)n * 256 + 2 * d2) = *(const uint*)(plds + n * 40 + 2 * d2);
  }
}

// ---------------------------------------------------------------- launch
extern "C" void kernel_launch(void* const* d_in, const int* in_sizes, int n_in,
                              void* d_out, int out_size, void* d_ws, size_t ws_size,
                              hipStream_t stream)
{
  const float* x    = (const float*)d_in[0];
  const float* gt   = (const float*)d_in[1];
  const float* q_w  = (const float*)d_in[2];
  const float* q_b  = (const float*)d_in[3];
  const float* kv_w = (const float*)d_in[4];
  const float* kv_b = (const float*)d_in[5];
  const float* sr_w = (const float*)d_in[6];
  const float* sr_b = (const float*)d_in[7];
  const float* nw   = (const float*)d_in[8];
  const float* nb   = (const float*)d_in[9];
  const float* p_w  = (const float*)d_in[10];
  const float* p_b  = (const float*)d_in[11];
  (void)in_sizes; (void)n_in; (void)out_size;

  if (ws_size < 204996608u) return;
  char* ws = (char*)d_ws;
  ushort* xc  = (ushort*)(ws);              // 34,078,720  (reused as att out)
  ushort* qb  = (ushort*)(ws + 34078720);   // 34,078,720  (Q-proj output)
  ushort* xkv = (ushort*)(ws + 68157440);   // 34,078,720
  ushort* kv  = (ushort*)(ws + 102236160);  // 68,157,440
  ushort* ccv = (ushort*)(ws + 170393600);  // 33,554,432
  ushort* wq  = (ushort*)(ws + 203948032);  // 131,072
  ushort* wkv = (ushort*)(ws + 204079104);  // 262,144
  ushort* wpr = (ushort*)(ws + 204341248);  // 131,072
  ushort* wcv = (ushort*)(ws + 204472320);  // 524,288

  float* out = (float*)d_out;
  float* out2 = out + 16777216 + 262144;    // skip

  k_prep<<<18688, 256, 0, stream>>>(x, gt, q_w, kv_w, p_w, sr_w,
                                    xc, xkv, out2, wq, wkv, wpr, wcv);
  k_gemm2<256><<<dim3(2, 520), 256, 0, stream>>>(xc, wq, q_b, qb);
  k_conv<<<1024, 512, 0, stream>>>(xc, wcv, ccv);
  k_ln<<<16384, 256, 0, stream>>>(ccv, sr_b, nw, nb, xkv);
  k_gemm2<512><<<dim3(4, 520), 256, 0, stream>>>(xkv, wkv, kv_b, kv);
  k_attn<<<2048, 256, 0, stream>>>(qb, kv, xc);
  k_gemm_out<<<dim3(2, 520), 256, 0, stream>>>(xc, wpr, p_b, out);
}